// Round 13
// baseline (124.392 us; speedup 1.0000x reference)
//
#include <hip/hip_runtime.h>
#include <hip/hip_bf16.h>

// B=8, Te=512, Td=128, D_ENC=D_DEC=512, ATT=256
// 3 kernels:
//  prep     : A,B -> fragment-swizzled bf16 hi/lo planes (r12-validated)
//  gemm_mfma: split-bf16 3-pass MFMA; epilogue stores Ew=exp2(2log2e*Wh),
//             Eu=exp2(2log2e*U)  (r12-validated)
//  fused_sc : per (b,4t): S = sum_a V*rcp(1+Ew*Eu) in regs -> softmax(-2S)
//             -> context + out_e.  Replaces scores_k + softctx + scoresP I/O.

typedef __attribute__((ext_vector_type(8))) short bf16x8;
typedef __attribute__((ext_vector_type(4))) float f32x4;

__device__ inline void f32_to_bf16_pair(float x, short& h, short& l) {
    unsigned u = __builtin_bit_cast(unsigned, x);
    unsigned r = u + 0x7FFFu + ((u >> 16) & 1u);           // RNE
    h = (short)(r >> 16);
    float xh = __builtin_bit_cast(float, r & 0xFFFF0000u);
    float xl = x - xh;
    unsigned u2 = __builtin_bit_cast(unsigned, xl);
    unsigned r2 = u2 + 0x7FFFu + ((u2 >> 16) & 1u);
    l = (short)(r2 >> 16);
}

// ---------------------------------------------------------------------------
// Kernel 0: merged prep (r12-validated, unchanged).
// ---------------------------------------------------------------------------
__global__ __launch_bounds__(256) void prep(
    const float* __restrict__ W_h, const float* __restrict__ U_a,
    const float* __restrict__ values, const float* __restrict__ query,
    short* __restrict__ BHi, short* __restrict__ BLo,
    short* __restrict__ AHi, short* __restrict__ ALo)
{
    __shared__ float TW[64][65];
    __shared__ float TA[16][516];
    const int bid = blockIdx.x;
    const int tid = threadIdx.x;

    if (bid < 64) {
        const int mat = bid >> 5, nb = (bid >> 3) & 3, kb = bid & 7;
        const float* W = mat ? U_a : W_h;
        {
            const int krow = tid >> 2, cq = (tid & 3) * 16;
            const float* src = W + (size_t)(kb * 64 + krow) * 256 + nb * 64 + cq;
            #pragma unroll
            for (int q = 0; q < 4; ++q)
                *(float4*)&TW[krow][cq + q * 4] = *(const float4*)&src[q * 4];
        }
        __syncthreads();
        {
            const int f = tid >> 5;
            const int ngl = f >> 1, ksl = f & 1;
            const int l0 = (tid & 31) * 2;
            const int ngrp = nb * 4 + ngl;
            const int ksg = kb * 2 + ksl;
            const size_t base = (size_t)mat * 131072 + (size_t)(ngrp * 16 + ksg) * 512;
            #pragma unroll
            for (int li = 0; li < 2; ++li) {
                const int lane = l0 + li;
                const int lr = lane & 15, lg = lane >> 4;
                bf16x8 hv, lv;
                #pragma unroll
                for (int j = 0; j < 8; ++j) {
                    short h, l;
                    f32_to_bf16_pair(TW[ksl * 32 + lg * 8 + j][ngl * 16 + lr], h, l);
                    hv[j] = h; lv[j] = l;
                }
                *(bf16x8*)(BHi + base + lane * 8) = hv;
                *(bf16x8*)(BLo + base + lane * 8) = lv;
            }
        }
    } else {
        const int mg = bid - 64;
        const float* src = (mg < 256) ? values + (size_t)mg * 16 * 512
                                      : query + (size_t)(mg - 256) * 16 * 512;
        {
            const int row = tid >> 4, c0 = (tid & 15) * 4;
            #pragma unroll
            for (int i = 0; i < 8; ++i)
                *(float4*)&TA[row][c0 + i * 64] =
                    *(const float4*)&src[(size_t)row * 512 + c0 + i * 64];
        }
        __syncthreads();
        {
            const int ks = tid >> 4;
            const int l4 = (tid & 15) * 4;
            const size_t base = ((size_t)(mg * 16 + ks)) * 512;
            #pragma unroll
            for (int li = 0; li < 4; ++li) {
                const int lane = l4 + li;
                const int lr = lane & 15, lg = lane >> 4;
                bf16x8 hv, lv;
                #pragma unroll
                for (int j = 0; j < 8; ++j) {
                    short h, l;
                    f32_to_bf16_pair(TA[lr][ks * 32 + lg * 8 + j], h, l);
                    hv[j] = h; lv[j] = l;
                }
                *(bf16x8*)(AHi + base + lane * 8) = hv;
                *(bf16x8*)(ALo + base + lane * 8) = lv;
            }
        }
    }
}

// ---------------------------------------------------------------------------
// Kernel 1: MFMA split-bf16 GEMM (r12-validated, unchanged).
// ---------------------------------------------------------------------------
__global__ __launch_bounds__(128) void gemm_mfma(
    const short* __restrict__ AHi, const short* __restrict__ ALo,
    const short* __restrict__ BHi, const short* __restrict__ BLo,
    float* __restrict__ EwO, float* __restrict__ EuO)
{
    const int bid = blockIdx.x;
    const int mt = bid >> 2, nt = bid & 3;
    const int tid = threadIdx.x;
    const int w = tid >> 6, l = tid & 63;
    const int lr = l & 15, lg = l >> 4;

    float* C; int m0, mg, matoff;
    if (mt < 128) { C = EwO; m0 = mt * 32; mg = mt * 2 + w; matoff = 0; }
    else { C = EuO; m0 = (mt - 128) * 32; mg = 256 + (mt - 128) * 2 + w; matoff = 131072; }

    const short* ah_p = AHi + ((size_t)mg * 16) * 512 + l * 8;
    const short* al_p = ALo + ((size_t)mg * 16) * 512 + l * 8;
    const short* bh_p = BHi + matoff + ((size_t)(nt * 4) * 16) * 512 + l * 8;
    const short* bl_p = BLo + matoff + ((size_t)(nt * 4) * 16) * 512 + l * 8;

    f32x4 acc[4];
    #pragma unroll
    for (int nc = 0; nc < 4; ++nc) acc[nc] = (f32x4){0.f, 0.f, 0.f, 0.f};

    #pragma unroll 2
    for (int ks = 0; ks < 16; ++ks) {
        bf16x8 ah = *(const bf16x8*)(ah_p + (size_t)ks * 512);
        bf16x8 al = *(const bf16x8*)(al_p + (size_t)ks * 512);
        #pragma unroll
        for (int nc = 0; nc < 4; ++nc) {
            bf16x8 bh = *(const bf16x8*)(bh_p + ((size_t)(nc * 16 + ks)) * 512);
            bf16x8 bl = *(const bf16x8*)(bl_p + ((size_t)(nc * 16 + ks)) * 512);
            acc[nc] = __builtin_amdgcn_mfma_f32_16x16x32_bf16(ah, bh, acc[nc], 0, 0, 0);
            acc[nc] = __builtin_amdgcn_mfma_f32_16x16x32_bf16(al, bh, acc[nc], 0, 0, 0);
            acc[nc] = __builtin_amdgcn_mfma_f32_16x16x32_bf16(ah, bl, acc[nc], 0, 0, 0);
        }
    }

    const float SCL = 2.8853900817779268f;  // 2*log2(e)
    float* cp = C + (size_t)(m0 + w * 16 + lg * 4) * 256 + nt * 64 + lr;
    #pragma unroll
    for (int nc = 0; nc < 4; ++nc)
        #pragma unroll
        for (int r = 0; r < 4; ++r)
            cp[(size_t)r * 256 + nc * 16] = __builtin_amdgcn_exp2f(acc[nc][r] * SCL);
}

// ---------------------------------------------------------------------------
// Kernel 2: fused scores + softmax + context.
// Grid 256 = 8b x 32 tg(4t), 512 thr (8 waves: wave w -> t=w>>1, half=w&1).
// Phase A: acc[sp] = sum_a V[a]*rcp(1 + Ew[s][a]*Eu[t][a]), s = sp*128+row,
//          Ew tiles [128][65] LDS-staged with register prefetch.
// Phase B: p = softmax(-2*acc) (shfl + cross-wave LDS), write out_e + Ps.
// Phase C: context from Ps + values (4-way s-split, LDS partial reduce).
// ---------------------------------------------------------------------------
struct FA { float Ws[128][65]; float Us[4][260]; float Vs[256]; float red[8]; };
struct FB { float Ps[4][512]; float Part[3][4][512]; };
union FS { FA a; FB b; };   // 38.5 KB; Us/Vs/red offsets > sizeof(FB): no alias

__global__ __launch_bounds__(512, 1) void fused_sc(
    const float* __restrict__ Ew, const float* __restrict__ Eu,
    const float* __restrict__ Va, const float* __restrict__ values,
    float* __restrict__ out_c, float* __restrict__ out_e)
{
    __shared__ FS sm;
    const int bid = blockIdx.x;
    const int b = bid & 7;               // XCD-pinned per batch
    const int t0 = (bid >> 3) * 4;
    const int tid = threadIdx.x;
    const int w = tid >> 6;              // 0..7
    const int t = w >> 1;                // 0..3 (wave-uniform)
    const int half = w & 1;
    const int lane = tid & 63;
    const int row = half * 64 + lane;    // 0..127

    // stage Eu rows (4x256) and V (256) once
    for (int k = tid; k < 1024; k += 512)
        sm.a.Us[k >> 8][k & 255] =
            Eu[(size_t)(b * 128 + t0 + (k >> 8)) * 256 + (k & 255)];
    if (tid < 256) sm.a.Vs[tid] = Va[tid];

    const int sr = tid >> 2;             // staging row 0..127
    const int scc = (tid & 3) * 16;      // staging col 0/16/32/48
    const float* ewb = Ew + (size_t)(b * 512) * 256;

    float4 pre[4];
    #pragma unroll
    for (int q = 0; q < 4; ++q)
        pre[q] = *(const float4*)&ewb[(size_t)sr * 256 + scc + q * 4];   // tile (sp0,ac0)
    #pragma unroll
    for (int q = 0; q < 4; ++q)
        *(float4*)&sm.a.Ws[sr][scc + q * 4] = pre[q];
    __syncthreads();

    float acc[4] = {};
    #pragma unroll
    for (int i = 0; i < 16; ++i) {           // fully unrolled: sp,ac compile-time
        const int sp = i >> 2, ac = i & 3;
        if (i < 15) {
            const int sp2 = (i + 1) >> 2, ac2 = (i + 1) & 3;
            #pragma unroll
            for (int q = 0; q < 4; ++q)
                pre[q] = *(const float4*)&ewb[(size_t)(sp2 * 128 + sr) * 256
                                              + ac2 * 64 + scc + q * 4];
        }
        float as = 0.f;
        const float* wr = &sm.a.Ws[row][0];
        const float* ur = &sm.a.Us[t][ac * 64];
        const float* vr = &sm.a.Vs[ac * 64];
        #pragma unroll 4
        for (int a4 = 0; a4 < 16; ++a4) {
            float4 wq = *(const float4*)&wr[a4 * 4];
            float4 uq = *(const float4*)&ur[a4 * 4];
            float4 vq = *(const float4*)&vr[a4 * 4];
            float e0 = fmaf(wq.x, uq.x, 1.f);     // 1 + Ew*Eu in one fma
            float e1 = fmaf(wq.y, uq.y, 1.f);
            float e2 = fmaf(wq.z, uq.z, 1.f);
            float e3 = fmaf(wq.w, uq.w, 1.f);
            as = fmaf(vq.x, __builtin_amdgcn_rcpf(e0), as);
            as = fmaf(vq.y, __builtin_amdgcn_rcpf(e1), as);
            as = fmaf(vq.z, __builtin_amdgcn_rcpf(e2), as);
            as = fmaf(vq.w, __builtin_amdgcn_rcpf(e3), as);
        }
        acc[sp] += as;
        __syncthreads();
        if (i < 15) {
            #pragma unroll
            for (int q = 0; q < 4; ++q)
                *(float4*)&sm.a.Ws[sr][scc + q * 4] = pre[q];
            __syncthreads();
        }
    }

    // Phase B: softmax(-2S) over 512 s per t (2 waves per t)
    const float SCL = 2.8853900817779268f;  // 2*log2(e)
    float ep[4]; float ssum = 0.f;
    #pragma unroll
    for (int sp = 0; sp < 4; ++sp) {
        ep[sp] = __builtin_amdgcn_exp2f(acc[sp] * -SCL);
        ssum += ep[sp];
    }
    #pragma unroll
    for (int off = 32; off > 0; off >>= 1)
        ssum += __shfl_xor(ssum, off);
    if (lane == 0) sm.a.red[w] = ssum;
    __syncthreads();
    const float inv = 1.0f / (sm.a.red[t * 2] + sm.a.red[t * 2 + 1]);

    float* erow = out_e + (size_t)(b * 128 + t0 + t) * 512;
    #pragma unroll
    for (int sp = 0; sp < 4; ++sp) {
        float p = ep[sp] * inv;
        sm.b.Ps[t][sp * 128 + row] = p;     // aliases dead Ws (synced above)
        erow[sp * 128 + row] = p;
    }
    __syncthreads();

    // Phase C: context. 4-way s-split, full 512-wide e per block.
    const int sh = tid >> 7;             // 0..3 (wave-uniform)
    const int el = (tid & 127) * 4;      // 0..508
    const int sb = sh * 128;
    const float* vb = values + (size_t)b * 262144;

    float4 a0 = {0,0,0,0}, a1 = {0,0,0,0}, a2 = {0,0,0,0}, a3 = {0,0,0,0};
    #pragma unroll 2
    for (int s2 = 0; s2 < 128; s2 += 4) {
        float4 q0 = *(const float4*)&sm.b.Ps[0][sb + s2];
        float4 q1 = *(const float4*)&sm.b.Ps[1][sb + s2];
        float4 q2 = *(const float4*)&sm.b.Ps[2][sb + s2];
        float4 q3 = *(const float4*)&sm.b.Ps[3][sb + s2];
        const float q0v[4] = {q0.x, q0.y, q0.z, q0.w};
        const float q1v[4] = {q1.x, q1.y, q1.z, q1.w};
        const float q2v[4] = {q2.x, q2.y, q2.z, q2.w};
        const float q3v[4] = {q3.x, q3.y, q3.z, q3.w};
        #pragma unroll
        for (int j = 0; j < 4; ++j) {
            float4 v4 = *(const float4*)&vb[(size_t)(sb + s2 + j) * 512 + el];
            a0.x = fmaf(q0v[j], v4.x, a0.x); a0.y = fmaf(q0v[j], v4.y, a0.y);
            a0.z = fmaf(q0v[j], v4.z, a0.z); a0.w = fmaf(q0v[j], v4.w, a0.w);
            a1.x = fmaf(q1v[j], v4.x, a1.x); a1.y = fmaf(q1v[j], v4.y, a1.y);
            a1.z = fmaf(q1v[j], v4.z, a1.z); a1.w = fmaf(q1v[j], v4.w, a1.w);
            a2.x = fmaf(q2v[j], v4.x, a2.x); a2.y = fmaf(q2v[j], v4.y, a2.y);
            a2.z = fmaf(q2v[j], v4.z, a2.z); a2.w = fmaf(q2v[j], v4.w, a2.w);
            a3.x = fmaf(q3v[j], v4.x, a3.x); a3.y = fmaf(q3v[j], v4.y, a3.y);
            a3.z = fmaf(q3v[j], v4.z, a3.z); a3.w = fmaf(q3v[j], v4.w, a3.w);
        }
    }

    if (sh) {
        *(float4*)&sm.b.Part[sh - 1][0][el] = a0;
        *(float4*)&sm.b.Part[sh - 1][1][el] = a1;
        *(float4*)&sm.b.Part[sh - 1][2][el] = a2;
        *(float4*)&sm.b.Part[sh - 1][3][el] = a3;
    }
    __syncthreads();
    if (!sh) {
        #pragma unroll
        for (int rrow = 0; rrow < 4; ++rrow) {
            float4 accv = (rrow == 0) ? a0 : (rrow == 1) ? a1 : (rrow == 2) ? a2 : a3;
            #pragma unroll
            for (int g = 0; g < 3; ++g) {
                float4 p4 = *(const float4*)&sm.b.Part[g][rrow][el];
                accv.x += p4.x; accv.y += p4.y; accv.z += p4.z; accv.w += p4.w;
            }
            *(float4*)&out_c[(size_t)(b * 128 + t0 + rrow) * 512 + el] = accv;
        }
    }
}

// ---------------------------------------------------------------------------
extern "C" void kernel_launch(void* const* d_in, const int* in_sizes, int n_in,
                              void* d_out, int out_size, void* d_ws, size_t ws_size,
                              hipStream_t stream) {
    const float* values = (const float*)d_in[0];  // [8,512,512]
    const float* query  = (const float*)d_in[1];  // [8,128,512]
    const float* W_h    = (const float*)d_in[2];  // [512,256]
    const float* U_a    = (const float*)d_in[3];  // [512,256]
    const float* V_a    = (const float*)d_in[4];  // [1,256]

    float* ws      = (float*)d_ws;
    float* Ew      = ws;                           // 4096*256 f32
    float* Eu      = ws + 1048576;                 // 1024*256 f32
    short* S       = (short*)(ws + 3407872);
    short* AHi     = S;                            // 5120*512 bf16
    short* ALo     = S + 2621440;
    short* BHi     = S + 5242880;                  // 2*256*512 bf16
    short* BLo     = S + 5505024;

    float* out_c = (float*)d_out;                  // [8,128,512]
    float* out_e = out_c + 8 * 128 * 512;          // [8,128,512]

    hipLaunchKernelGGL(prep, dim3(384), dim3(256), 0, stream,
                       W_h, U_a, values, query, BHi, BLo, AHi, ALo);
    hipLaunchKernelGGL(gemm_mfma, dim3(640), dim3(128), 0, stream,
                       AHi, ALo, BHi, BLo, Ew, Eu);
    hipLaunchKernelGGL(fused_sc, dim3(256), dim3(512), 0, stream,
                       Ew, Eu, V_a, values, out_c, out_e);
}

// Round 14
// 56.093 us; speedup vs baseline: 2.2176x; 2.2176x over previous
//
#include <hip/hip_runtime.h>
#include <hip/hip_bf16.h>

// B=8, Te=512, Td=128, D_ENC=D_DEC=512, ATT=256
// Round-12 validated structure + fmaf-merged scores inner loop:
//  prep      : A,B -> fragment-swizzled bf16 hi/lo planes
//  gemm_mfma : split-bf16 3-pass MFMA; epilogue stores Ew=exp2(2log2e*Wh),
//              Eu=exp2(2log2e*U)  (exp2(w+u) = Ew*Eu factorization)
//  scores_k  : S = sum_a V[a]*rcp(fmaf(Ew,Eu,1))  (2 VALU + 1 trans per elem)
//  softctx   : p = softmax(-2S); context + out_e  (e-split 4)

typedef __attribute__((ext_vector_type(8))) short bf16x8;
typedef __attribute__((ext_vector_type(4))) float f32x4;

__device__ inline void f32_to_bf16_pair(float x, short& h, short& l) {
    unsigned u = __builtin_bit_cast(unsigned, x);
    unsigned r = u + 0x7FFFu + ((u >> 16) & 1u);           // RNE
    h = (short)(r >> 16);
    float xh = __builtin_bit_cast(float, r & 0xFFFF0000u);
    float xl = x - xh;
    unsigned u2 = __builtin_bit_cast(unsigned, xl);
    unsigned r2 = u2 + 0x7FFFu + ((u2 >> 16) & 1u);
    l = (short)(r2 >> 16);
}

// ---------------------------------------------------------------------------
// Kernel 0: merged prep.  bid<64: W_h/U_a -> swizzled B planes (2mat x 4nb x 8kb).
// bid>=64: values/query -> swizzled A planes (mg = bid-64, 0..319).
// Fragment-linear: frag(16 rows x 32 k) -> offset = frag_id*512 + lane*8 + j.
// ---------------------------------------------------------------------------
__global__ __launch_bounds__(256) void prep(
    const float* __restrict__ W_h, const float* __restrict__ U_a,
    const float* __restrict__ values, const float* __restrict__ query,
    short* __restrict__ BHi, short* __restrict__ BLo,
    short* __restrict__ AHi, short* __restrict__ ALo)
{
    __shared__ float TW[64][65];
    __shared__ float TA[16][516];
    const int bid = blockIdx.x;
    const int tid = threadIdx.x;

    if (bid < 64) {
        const int mat = bid >> 5, nb = (bid >> 3) & 3, kb = bid & 7;
        const float* W = mat ? U_a : W_h;
        {
            const int krow = tid >> 2, cq = (tid & 3) * 16;
            const float* src = W + (size_t)(kb * 64 + krow) * 256 + nb * 64 + cq;
            #pragma unroll
            for (int q = 0; q < 4; ++q)
                *(float4*)&TW[krow][cq + q * 4] = *(const float4*)&src[q * 4];
        }
        __syncthreads();
        {
            const int f = tid >> 5;
            const int ngl = f >> 1, ksl = f & 1;
            const int l0 = (tid & 31) * 2;
            const int ngrp = nb * 4 + ngl;
            const int ksg = kb * 2 + ksl;
            const size_t base = (size_t)mat * 131072 + (size_t)(ngrp * 16 + ksg) * 512;
            #pragma unroll
            for (int li = 0; li < 2; ++li) {
                const int lane = l0 + li;
                const int lr = lane & 15, lg = lane >> 4;
                bf16x8 hv, lv;
                #pragma unroll
                for (int j = 0; j < 8; ++j) {
                    short h, l;
                    f32_to_bf16_pair(TW[ksl * 32 + lg * 8 + j][ngl * 16 + lr], h, l);
                    hv[j] = h; lv[j] = l;
                }
                *(bf16x8*)(BHi + base + lane * 8) = hv;
                *(bf16x8*)(BLo + base + lane * 8) = lv;
            }
        }
    } else {
        const int mg = bid - 64;
        const float* src = (mg < 256) ? values + (size_t)mg * 16 * 512
                                      : query + (size_t)(mg - 256) * 16 * 512;
        {
            const int row = tid >> 4, c0 = (tid & 15) * 4;
            #pragma unroll
            for (int i = 0; i < 8; ++i)
                *(float4*)&TA[row][c0 + i * 64] =
                    *(const float4*)&src[(size_t)row * 512 + c0 + i * 64];
        }
        __syncthreads();
        {
            const int ks = tid >> 4;
            const int l4 = (tid & 15) * 4;
            const size_t base = ((size_t)(mg * 16 + ks)) * 512;
            #pragma unroll
            for (int li = 0; li < 4; ++li) {
                const int lane = l4 + li;
                const int lr = lane & 15, lg = lane >> 4;
                bf16x8 hv, lv;
                #pragma unroll
                for (int j = 0; j < 8; ++j) {
                    short h, l;
                    f32_to_bf16_pair(TA[lr][ks * 32 + lg * 8 + j], h, l);
                    hv[j] = h; lv[j] = l;
                }
                *(bf16x8*)(AHi + base + lane * 8) = hv;
                *(bf16x8*)(ALo + base + lane * 8) = lv;
            }
        }
    }
}

// ---------------------------------------------------------------------------
// Kernel 1: MFMA split-bf16 GEMM (3-pass), swizzled-coalesced operands.
// Grid 640 = 160 mt(32 rows) x 4 nt(64 cols), 128 thr = 2 waves.
// Epilogue: store Ew/Eu = exp2(acc * 2log2e).
// ---------------------------------------------------------------------------
__global__ __launch_bounds__(128) void gemm_mfma(
    const short* __restrict__ AHi, const short* __restrict__ ALo,
    const short* __restrict__ BHi, const short* __restrict__ BLo,
    float* __restrict__ EwO, float* __restrict__ EuO)
{
    const int bid = blockIdx.x;
    const int mt = bid >> 2, nt = bid & 3;
    const int tid = threadIdx.x;
    const int w = tid >> 6, l = tid & 63;
    const int lr = l & 15, lg = l >> 4;

    float* C; int m0, mg, matoff;
    if (mt < 128) { C = EwO; m0 = mt * 32; mg = mt * 2 + w; matoff = 0; }
    else { C = EuO; m0 = (mt - 128) * 32; mg = 256 + (mt - 128) * 2 + w; matoff = 131072; }

    const short* ah_p = AHi + ((size_t)mg * 16) * 512 + l * 8;
    const short* al_p = ALo + ((size_t)mg * 16) * 512 + l * 8;
    const short* bh_p = BHi + matoff + ((size_t)(nt * 4) * 16) * 512 + l * 8;
    const short* bl_p = BLo + matoff + ((size_t)(nt * 4) * 16) * 512 + l * 8;

    f32x4 acc[4];
    #pragma unroll
    for (int nc = 0; nc < 4; ++nc) acc[nc] = (f32x4){0.f, 0.f, 0.f, 0.f};

    #pragma unroll 2
    for (int ks = 0; ks < 16; ++ks) {
        bf16x8 ah = *(const bf16x8*)(ah_p + (size_t)ks * 512);
        bf16x8 al = *(const bf16x8*)(al_p + (size_t)ks * 512);
        #pragma unroll
        for (int nc = 0; nc < 4; ++nc) {
            bf16x8 bh = *(const bf16x8*)(bh_p + ((size_t)(nc * 16 + ks)) * 512);
            bf16x8 bl = *(const bf16x8*)(bl_p + ((size_t)(nc * 16 + ks)) * 512);
            acc[nc] = __builtin_amdgcn_mfma_f32_16x16x32_bf16(ah, bh, acc[nc], 0, 0, 0);
            acc[nc] = __builtin_amdgcn_mfma_f32_16x16x32_bf16(al, bh, acc[nc], 0, 0, 0);
            acc[nc] = __builtin_amdgcn_mfma_f32_16x16x32_bf16(ah, bl, acc[nc], 0, 0, 0);
        }
    }

    const float SCL = 2.8853900817779268f;  // 2*log2(e)
    float* cp = C + (size_t)(m0 + w * 16 + lg * 4) * 256 + nt * 64 + lr;
    #pragma unroll
    for (int nc = 0; nc < 4; ++nc)
        #pragma unroll
        for (int r = 0; r < 4; ++r)
            cp[(size_t)r * 256 + nc * 16] = __builtin_amdgcn_exp2f(acc[nc][r] * SCL);
}

// ---------------------------------------------------------------------------
// Kernel 2: score partials.  Grid 2048 = 8b x 4ah x 8tt x 8st, 256 thr.
// Block = 16t x 64s x 64a; thread: 1t x 4s.
// S = sum_a V[a] * rcp(fmaf(Ew, Eu, 1))    (2 VALU + 1 trans per element)
// ---------------------------------------------------------------------------
__global__ __launch_bounds__(256) void scores_k(
    const float* __restrict__ Ew, const float* __restrict__ Eu,
    const float* __restrict__ Va, float* __restrict__ scoresP)
{
    __shared__ float Ws[64][68];
    __shared__ float Us[16][68];

    const int bid = blockIdx.x;
    const int b = bid & 7;               // XCD-pinned per batch
    const int rest = bid >> 3;
    const int ah = rest & 3;
    const int tt = (rest >> 2) & 7;
    const int st = rest >> 5;
    const int t0 = tt * 16, s0 = st * 64, a0 = ah * 64;
    const int tid = threadIdx.x;

    const int r = tid >> 2, c16 = (tid & 3) * 16;
    const float* wsrc = Ew + (size_t)(b * 512 + s0 + r) * 256 + a0 + c16;
    #pragma unroll
    for (int q = 0; q < 4; ++q)
        *(float4*)&Ws[r][c16 + q * 4] = *(const float4*)&wsrc[q * 4];
    const int r8 = tid >> 4, c8 = (tid & 15) * 4;
    const float* usrc = Eu + (size_t)(b * 128 + t0 + r8) * 256 + a0 + c8;
    *(float4*)&Us[r8][c8] = *(const float4*)&usrc[0];
    __syncthreads();

    const int t = tid >> 4;
    const int ss = tid & 15;
    const float* Vp = Va + a0;

    float acc[4] = {};
    #pragma unroll 4
    for (int a = 0; a < 64; a += 4) {
        float4 u  = *(const float4*)&Us[t][a];
        float4 w0 = *(const float4*)&Ws[ss][a];
        float4 w1 = *(const float4*)&Ws[ss + 16][a];
        float4 w2 = *(const float4*)&Ws[ss + 32][a];
        float4 w3 = *(const float4*)&Ws[ss + 48][a];
        const float uv[4] = {u.x, u.y, u.z, u.w};
        const float wv[4][4] = {{w0.x, w0.y, w0.z, w0.w}, {w1.x, w1.y, w1.z, w1.w},
                                {w2.x, w2.y, w2.z, w2.w}, {w3.x, w3.y, w3.z, w3.w}};
        #pragma unroll
        for (int q = 0; q < 4; ++q) {
            const float vq = Vp[a + q];  // wave-uniform -> scalar load
            #pragma unroll
            for (int k = 0; k < 4; ++k) {
                float rc = __builtin_amdgcn_rcpf(fmaf(wv[k][q], uv[q], 1.f));
                acc[k] = fmaf(vq, rc, acc[k]);
            }
        }
    }

    float* sp = scoresP + (size_t)ah * 524288
              + (size_t)(b * 128 + t0 + t) * 512 + s0 + ss;
    #pragma unroll
    for (int k = 0; k < 4; ++k) sp[k * 16] = acc[k];
}

// ---------------------------------------------------------------------------
// Kernel 3: combine partials + softmax + context.
// Grid 1024 = 8b x 32 tg(4t) x 4 eh, 256 thr.  p = softmax(-2*S).
// ---------------------------------------------------------------------------
__global__ __launch_bounds__(256) void softctx(
    const float* __restrict__ scoresP, const float* __restrict__ values,
    float* __restrict__ out_c, float* __restrict__ out_e)
{
    __shared__ float Ps[4][512];
    __shared__ float Part[7][4][128];

    const int bid = blockIdx.x;
    const int b = bid & 7;
    const int rest = bid >> 3;
    const int tg = rest & 31;
    const int eh = rest >> 5;          // 0..3
    const int t0 = tg * 4;
    const int tid = threadIdx.x;

    {
        const int row = tid >> 6, lane = tid & 63;  // one wave per t-row
        const float* sp = scoresP + (size_t)(b * 128 + t0 + row) * 512;
        float e[8]; float ssum = 0.f;
        #pragma unroll
        for (int k = 0; k < 8; ++k) {
            const int idx = k * 64 + lane;
            float s = sp[idx] + sp[524288 + idx] + sp[1048576 + idx] + sp[1572864 + idx];
            e[k] = __builtin_amdgcn_exp2f(s * -2.8853900817779268f);  // exp(-2S)
            ssum += e[k];
        }
        #pragma unroll
        for (int off = 32; off > 0; off >>= 1)
            ssum += __shfl_xor(ssum, off);
        const float inv = 1.0f / ssum;
        float* erow = out_e + (size_t)(b * 128 + t0 + row) * 512;
        #pragma unroll
        for (int k = 0; k < 8; ++k) {
            float p = e[k] * inv;
            Ps[row][k * 64 + lane] = p;
            if (eh == 0) erow[k * 64 + lane] = p;
        }
    }
    __syncthreads();

    const int sh = tid >> 5;          // 0..7
    const int el = (tid & 31) * 4;    // 0..124
    const int e4 = eh * 128 + el;
    const int sb = sh * 64;
    const float* vb = values + (size_t)b * 262144;

    float4 a0 = {0,0,0,0}, a1 = {0,0,0,0}, a2 = {0,0,0,0}, a3 = {0,0,0,0};
    #pragma unroll 2
    for (int s2 = 0; s2 < 64; s2 += 4) {
        float4 q0 = *(const float4*)&Ps[0][sb + s2];
        float4 q1 = *(const float4*)&Ps[1][sb + s2];
        float4 q2 = *(const float4*)&Ps[2][sb + s2];
        float4 q3 = *(const float4*)&Ps[3][sb + s2];
        const float q0v[4] = {q0.x, q0.y, q0.z, q0.w};
        const float q1v[4] = {q1.x, q1.y, q1.z, q1.w};
        const float q2v[4] = {q2.x, q2.y, q2.z, q2.w};
        const float q3v[4] = {q3.x, q3.y, q3.z, q3.w};
        #pragma unroll
        for (int j = 0; j < 4; ++j) {
            float4 v4 = *(const float4*)&vb[(size_t)(sb + s2 + j) * 512 + e4];
            a0.x = fmaf(q0v[j], v4.x, a0.x); a0.y = fmaf(q0v[j], v4.y, a0.y);
            a0.z = fmaf(q0v[j], v4.z, a0.z); a0.w = fmaf(q0v[j], v4.w, a0.w);
            a1.x = fmaf(q1v[j], v4.x, a1.x); a1.y = fmaf(q1v[j], v4.y, a1.y);
            a1.z = fmaf(q1v[j], v4.z, a1.z); a1.w = fmaf(q1v[j], v4.w, a1.w);
            a2.x = fmaf(q2v[j], v4.x, a2.x); a2.y = fmaf(q2v[j], v4.y, a2.y);
            a2.z = fmaf(q2v[j], v4.z, a2.z); a2.w = fmaf(q2v[j], v4.w, a2.w);
            a3.x = fmaf(q3v[j], v4.x, a3.x); a3.y = fmaf(q3v[j], v4.y, a3.y);
            a3.z = fmaf(q3v[j], v4.z, a3.z); a3.w = fmaf(q3v[j], v4.w, a3.w);
        }
    }

    if (sh) {
        *(float4*)&Part[sh - 1][0][el] = a0;
        *(float4*)&Part[sh - 1][1][el] = a1;
        *(float4*)&Part[sh - 1][2][el] = a2;
        *(float4*)&Part[sh - 1][3][el] = a3;
    }
    __syncthreads();
    if (!sh) {
        #pragma unroll
        for (int rrow = 0; rrow < 4; ++rrow) {
            float4 acc = (rrow == 0) ? a0 : (rrow == 1) ? a1 : (rrow == 2) ? a2 : a3;
            #pragma unroll
            for (int g = 0; g < 7; ++g) {
                float4 p4 = *(const float4*)&Part[g][rrow][el];
                acc.x += p4.x; acc.y += p4.y; acc.z += p4.z; acc.w += p4.w;
            }
            *(float4*)&out_c[(size_t)(b * 128 + t0 + rrow) * 512 + e4] = acc;
        }
    }
}

// ---------------------------------------------------------------------------
extern "C" void kernel_launch(void* const* d_in, const int* in_sizes, int n_in,
                              void* d_out, int out_size, void* d_ws, size_t ws_size,
                              hipStream_t stream) {
    const float* values = (const float*)d_in[0];  // [8,512,512]
    const float* query  = (const float*)d_in[1];  // [8,128,512]
    const float* W_h    = (const float*)d_in[2];  // [512,256]
    const float* U_a    = (const float*)d_in[3];  // [512,256]
    const float* V_a    = (const float*)d_in[4];  // [1,256]

    float* ws      = (float*)d_ws;
    float* Ew      = ws;                           // 4096*256 f32
    float* Eu      = ws + 1048576;                 // 1024*256 f32
    float* scoresP = ws + 1310720;                 // 4 * 524288 f32
    short* S       = (short*)(ws + 3407872);
    short* AHi     = S;                            // 5120*512 bf16
    short* ALo     = S + 2621440;
    short* BHi     = S + 5242880;                  // 2*256*512 bf16
    short* BLo     = S + 5505024;

    float* out_c = (float*)d_out;                  // [8,128,512]
    float* out_e = out_c + 8 * 128 * 512;          // [8,128,512]

    hipLaunchKernelGGL(prep, dim3(384), dim3(256), 0, stream,
                       W_h, U_a, values, query, BHi, BLo, AHi, ALo);
    hipLaunchKernelGGL(gemm_mfma, dim3(640), dim3(128), 0, stream,
                       AHi, ALo, BHi, BLo, Ew, Eu);
    hipLaunchKernelGGL(scores_k, dim3(2048), dim3(256), 0, stream,
                       Ew, Eu, V_a, scoresP);
    hipLaunchKernelGGL(softctx, dim3(1024), dim3(256), 0, stream,
                       scoresP, values, out_c, out_e);
}

// Round 15
// 52.739 us; speedup vs baseline: 2.3586x; 1.0636x over previous
//
#include <hip/hip_runtime.h>
#include <hip/hip_bf16.h>

// B=8, Te=512, Td=128, D_ENC=D_DEC=512, ATT=256
//  prep      : A,B -> fragment-swizzled bf16 hi/lo planes
//  gemm_mfma : split-bf16 3-pass MFMA; epilogue stores Ew/Eu = exp2(2log2e*x)
//  scores_k  : S = sum_a V[a]*rcp(fmaf(Ew,Eu,1)), 2t x 4s micro-tile
//  softctx   : p = softmax(-2S); context + out_e  (8t per block, e-split 4)

typedef __attribute__((ext_vector_type(8))) short bf16x8;
typedef __attribute__((ext_vector_type(4))) float f32x4;

__device__ inline void f32_to_bf16_pair(float x, short& h, short& l) {
    unsigned u = __builtin_bit_cast(unsigned, x);
    unsigned r = u + 0x7FFFu + ((u >> 16) & 1u);           // RNE
    h = (short)(r >> 16);
    float xh = __builtin_bit_cast(float, r & 0xFFFF0000u);
    float xl = x - xh;
    unsigned u2 = __builtin_bit_cast(unsigned, xl);
    unsigned r2 = u2 + 0x7FFFu + ((u2 >> 16) & 1u);
    l = (short)(r2 >> 16);
}

// ---------------------------------------------------------------------------
// Kernel 0: merged prep (r12-validated, unchanged).
// ---------------------------------------------------------------------------
__global__ __launch_bounds__(256) void prep(
    const float* __restrict__ W_h, const float* __restrict__ U_a,
    const float* __restrict__ values, const float* __restrict__ query,
    short* __restrict__ BHi, short* __restrict__ BLo,
    short* __restrict__ AHi, short* __restrict__ ALo)
{
    __shared__ float TW[64][65];
    __shared__ float TA[16][516];
    const int bid = blockIdx.x;
    const int tid = threadIdx.x;

    if (bid < 64) {
        const int mat = bid >> 5, nb = (bid >> 3) & 3, kb = bid & 7;
        const float* W = mat ? U_a : W_h;
        {
            const int krow = tid >> 2, cq = (tid & 3) * 16;
            const float* src = W + (size_t)(kb * 64 + krow) * 256 + nb * 64 + cq;
            #pragma unroll
            for (int q = 0; q < 4; ++q)
                *(float4*)&TW[krow][cq + q * 4] = *(const float4*)&src[q * 4];
        }
        __syncthreads();
        {
            const int f = tid >> 5;
            const int ngl = f >> 1, ksl = f & 1;
            const int l0 = (tid & 31) * 2;
            const int ngrp = nb * 4 + ngl;
            const int ksg = kb * 2 + ksl;
            const size_t base = (size_t)mat * 131072 + (size_t)(ngrp * 16 + ksg) * 512;
            #pragma unroll
            for (int li = 0; li < 2; ++li) {
                const int lane = l0 + li;
                const int lr = lane & 15, lg = lane >> 4;
                bf16x8 hv, lv;
                #pragma unroll
                for (int j = 0; j < 8; ++j) {
                    short h, l;
                    f32_to_bf16_pair(TW[ksl * 32 + lg * 8 + j][ngl * 16 + lr], h, l);
                    hv[j] = h; lv[j] = l;
                }
                *(bf16x8*)(BHi + base + lane * 8) = hv;
                *(bf16x8*)(BLo + base + lane * 8) = lv;
            }
        }
    } else {
        const int mg = bid - 64;
        const float* src = (mg < 256) ? values + (size_t)mg * 16 * 512
                                      : query + (size_t)(mg - 256) * 16 * 512;
        {
            const int row = tid >> 4, c0 = (tid & 15) * 4;
            #pragma unroll
            for (int i = 0; i < 8; ++i)
                *(float4*)&TA[row][c0 + i * 64] =
                    *(const float4*)&src[(size_t)row * 512 + c0 + i * 64];
        }
        __syncthreads();
        {
            const int ks = tid >> 4;
            const int l4 = (tid & 15) * 4;
            const size_t base = ((size_t)(mg * 16 + ks)) * 512;
            #pragma unroll
            for (int li = 0; li < 4; ++li) {
                const int lane = l4 + li;
                const int lr = lane & 15, lg = lane >> 4;
                bf16x8 hv, lv;
                #pragma unroll
                for (int j = 0; j < 8; ++j) {
                    short h, l;
                    f32_to_bf16_pair(TA[lr][ks * 32 + lg * 8 + j], h, l);
                    hv[j] = h; lv[j] = l;
                }
                *(bf16x8*)(AHi + base + lane * 8) = hv;
                *(bf16x8*)(ALo + base + lane * 8) = lv;
            }
        }
    }
}

// ---------------------------------------------------------------------------
// Kernel 1: MFMA split-bf16 GEMM (r12-validated, unchanged).
// ---------------------------------------------------------------------------
__global__ __launch_bounds__(128) void gemm_mfma(
    const short* __restrict__ AHi, const short* __restrict__ ALo,
    const short* __restrict__ BHi, const short* __restrict__ BLo,
    float* __restrict__ EwO, float* __restrict__ EuO)
{
    const int bid = blockIdx.x;
    const int mt = bid >> 2, nt = bid & 3;
    const int tid = threadIdx.x;
    const int w = tid >> 6, l = tid & 63;
    const int lr = l & 15, lg = l >> 4;

    float* C; int m0, mg, matoff;
    if (mt < 128) { C = EwO; m0 = mt * 32; mg = mt * 2 + w; matoff = 0; }
    else { C = EuO; m0 = (mt - 128) * 32; mg = 256 + (mt - 128) * 2 + w; matoff = 131072; }

    const short* ah_p = AHi + ((size_t)mg * 16) * 512 + l * 8;
    const short* al_p = ALo + ((size_t)mg * 16) * 512 + l * 8;
    const short* bh_p = BHi + matoff + ((size_t)(nt * 4) * 16) * 512 + l * 8;
    const short* bl_p = BLo + matoff + ((size_t)(nt * 4) * 16) * 512 + l * 8;

    f32x4 acc[4];
    #pragma unroll
    for (int nc = 0; nc < 4; ++nc) acc[nc] = (f32x4){0.f, 0.f, 0.f, 0.f};

    #pragma unroll 2
    for (int ks = 0; ks < 16; ++ks) {
        bf16x8 ah = *(const bf16x8*)(ah_p + (size_t)ks * 512);
        bf16x8 al = *(const bf16x8*)(al_p + (size_t)ks * 512);
        #pragma unroll
        for (int nc = 0; nc < 4; ++nc) {
            bf16x8 bh = *(const bf16x8*)(bh_p + ((size_t)(nc * 16 + ks)) * 512);
            bf16x8 bl = *(const bf16x8*)(bl_p + ((size_t)(nc * 16 + ks)) * 512);
            acc[nc] = __builtin_amdgcn_mfma_f32_16x16x32_bf16(ah, bh, acc[nc], 0, 0, 0);
            acc[nc] = __builtin_amdgcn_mfma_f32_16x16x32_bf16(al, bh, acc[nc], 0, 0, 0);
            acc[nc] = __builtin_amdgcn_mfma_f32_16x16x32_bf16(ah, bl, acc[nc], 0, 0, 0);
        }
    }

    const float SCL = 2.8853900817779268f;  // 2*log2(e)
    float* cp = C + (size_t)(m0 + w * 16 + lg * 4) * 256 + nt * 64 + lr;
    #pragma unroll
    for (int nc = 0; nc < 4; ++nc)
        #pragma unroll
        for (int r = 0; r < 4; ++r)
            cp[(size_t)r * 256 + nc * 16] = __builtin_amdgcn_exp2f(acc[nc][r] * SCL);
}

// ---------------------------------------------------------------------------
// Kernel 2: score partials, 2t x 4s micro-tile (r5-validated shape).
// Grid 1024 = 8b x 4ah x 4tt x 8st, 256 thr.  Block = 32t x 64s x 64a.
// S = sum_a V[a] * rcp(fmaf(Ew, Eu, 1)).  LDS: 6 b128 reads / 32 elems.
// ---------------------------------------------------------------------------
__global__ __launch_bounds__(256) void scores_k(
    const float* __restrict__ Ew, const float* __restrict__ Eu,
    const float* __restrict__ Va, float* __restrict__ scoresP)
{
    __shared__ float Ws[64][68];
    __shared__ float Us[32][68];

    const int bid = blockIdx.x;
    const int b = bid & 7;               // XCD-pinned per batch
    const int rest = bid >> 3;           // 0..127
    const int ah = rest & 3;
    const int tt = (rest >> 2) & 3;      // 4 t-tiles of 32
    const int st = rest >> 4;            // 8 s-tiles of 64
    const int t0 = tt * 32, s0 = st * 64, a0 = ah * 64;
    const int tid = threadIdx.x;

    {   // stage Ew (64s x 64a) and Eu (32t x 64a)
        const int r = tid >> 2, c16 = (tid & 3) * 16;
        const float* wsrc = Ew + (size_t)(b * 512 + s0 + r) * 256 + a0 + c16;
        #pragma unroll
        for (int q = 0; q < 4; ++q)
            *(float4*)&Ws[r][c16 + q * 4] = *(const float4*)&wsrc[q * 4];
        const int r8 = tid >> 3, c8 = (tid & 7) * 8;
        const float* usrc = Eu + (size_t)(b * 128 + t0 + r8) * 256 + a0 + c8;
        *(float4*)&Us[r8][c8]     = *(const float4*)&usrc[0];
        *(float4*)&Us[r8][c8 + 4] = *(const float4*)&usrc[4];
    }
    __syncthreads();

    const int tb = tid >> 4;             // t rows {tb, tb+16}
    const int ss = tid & 15;             // s rows {ss, ss+16, ss+32, ss+48}
    const float* Vp = Va + a0;

    float acc[2][4] = {};
    #pragma unroll 2
    for (int a = 0; a < 64; a += 4) {
        float4 u0 = *(const float4*)&Us[tb][a];
        float4 u1 = *(const float4*)&Us[tb + 16][a];
        float4 w0 = *(const float4*)&Ws[ss][a];
        float4 w1 = *(const float4*)&Ws[ss + 16][a];
        float4 w2 = *(const float4*)&Ws[ss + 32][a];
        float4 w3 = *(const float4*)&Ws[ss + 48][a];
        const float uv[2][4] = {{u0.x, u0.y, u0.z, u0.w}, {u1.x, u1.y, u1.z, u1.w}};
        const float wv[4][4] = {{w0.x, w0.y, w0.z, w0.w}, {w1.x, w1.y, w1.z, w1.w},
                                {w2.x, w2.y, w2.z, w2.w}, {w3.x, w3.y, w3.z, w3.w}};
        #pragma unroll
        for (int q = 0; q < 4; ++q) {
            const float vq = Vp[a + q];  // wave-uniform -> scalar load
            #pragma unroll
            for (int i = 0; i < 2; ++i)
                #pragma unroll
                for (int k = 0; k < 4; ++k) {
                    float rc = __builtin_amdgcn_rcpf(fmaf(wv[k][q], uv[i][q], 1.f));
                    acc[i][k] = fmaf(vq, rc, acc[i][k]);
                }
        }
    }

    float* sp = scoresP + (size_t)ah * 524288
              + (size_t)(b * 128 + t0 + tb) * 512 + s0 + ss;
    #pragma unroll
    for (int k = 0; k < 4; ++k) sp[k * 16] = acc[0][k];
    sp += (size_t)16 * 512;
    #pragma unroll
    for (int k = 0; k < 4; ++k) sp[k * 16] = acc[1][k];
}

// ---------------------------------------------------------------------------
// Kernel 3: combine partials + softmax + context, 8t per block.
// Grid 512 = 8b x 16 tg(8t) x 4 eh, 256 thr.  p = softmax(-2*S).
// Softmax: half-wave (32-lane) per t-row; ctx: s-split 8, 128-wide e-slice.
// ---------------------------------------------------------------------------
__global__ __launch_bounds__(256) void softctx(
    const float* __restrict__ scoresP, const float* __restrict__ values,
    float* __restrict__ out_c, float* __restrict__ out_e)
{
    __shared__ float Ps[8][512];
    __shared__ float Part[7][8][128];

    const int bid = blockIdx.x;
    const int b = bid & 7;
    const int rest = bid >> 3;         // 0..63
    const int tg = rest & 15;
    const int eh = rest >> 4;          // 0..3
    const int t0 = tg * 8;
    const int tid = threadIdx.x;

    {   // softmax: row = tid>>5 (0..7), 32 lanes per row
        const int row = tid >> 5, lane = tid & 31;
        const float* sp = scoresP + (size_t)(b * 128 + t0 + row) * 512;
        float e[16]; float ssum = 0.f;
        #pragma unroll
        for (int k = 0; k < 16; ++k) {
            const int idx = k * 32 + lane;
            float s = sp[idx] + sp[524288 + idx] + sp[1048576 + idx] + sp[1572864 + idx];
            e[k] = __builtin_amdgcn_exp2f(s * -2.8853900817779268f);  // exp(-2S)
            ssum += e[k];
        }
        #pragma unroll
        for (int off = 16; off > 0; off >>= 1)      // stays within 32-lane group
            ssum += __shfl_xor(ssum, off);
        const float inv = 1.0f / ssum;
        float* erow = out_e + (size_t)(b * 128 + t0 + row) * 512;
        #pragma unroll
        for (int k = 0; k < 16; ++k) {
            float p = e[k] * inv;
            Ps[row][k * 32 + lane] = p;
            if (eh == 0) erow[k * 32 + lane] = p;
        }
    }
    __syncthreads();

    const int sh = tid >> 5;           // 0..7 s-split
    const int el = (tid & 31) * 4;     // 0..124
    const int e4 = eh * 128 + el;
    const int sb = sh * 64;
    const float* vb = values + (size_t)b * 262144;

    f32x4 a[8];
    #pragma unroll
    for (int r = 0; r < 8; ++r) a[r] = (f32x4){0.f, 0.f, 0.f, 0.f};

    #pragma unroll 2
    for (int s2 = 0; s2 < 64; s2 += 4) {
        float4 q[8];
        #pragma unroll
        for (int r = 0; r < 8; ++r)
            q[r] = *(const float4*)&Ps[r][sb + s2];
        #pragma unroll
        for (int j = 0; j < 4; ++j) {
            float4 v4 = *(const float4*)&vb[(size_t)(sb + s2 + j) * 512 + e4];
            #pragma unroll
            for (int r = 0; r < 8; ++r) {
                const float qv = (j == 0) ? q[r].x : (j == 1) ? q[r].y
                               : (j == 2) ? q[r].z : q[r].w;
                a[r][0] = fmaf(qv, v4.x, a[r][0]);
                a[r][1] = fmaf(qv, v4.y, a[r][1]);
                a[r][2] = fmaf(qv, v4.z, a[r][2]);
                a[r][3] = fmaf(qv, v4.w, a[r][3]);
            }
        }
    }

    if (sh) {
        #pragma unroll
        for (int r = 0; r < 8; ++r)
            *(f32x4*)&Part[sh - 1][r][el] = a[r];
    }
    __syncthreads();
    if (!sh) {
        #pragma unroll
        for (int r = 0; r < 8; ++r) {
            f32x4 accv = a[r];
            #pragma unroll
            for (int g = 0; g < 7; ++g) {
                float4 p4 = *(const float4*)&Part[g][r][el];
                accv[0] += p4.x; accv[1] += p4.y; accv[2] += p4.z; accv[3] += p4.w;
            }
            *(f32x4*)&out_c[(size_t)(b * 128 + t0 + r) * 512 + e4] = accv;
        }
    }
}

// ---------------------------------------------------------------------------
extern "C" void kernel_launch(void* const* d_in, const int* in_sizes, int n_in,
                              void* d_out, int out_size, void* d_ws, size_t ws_size,
                              hipStream_t stream) {
    const float* values = (const float*)d_in[0];  // [8,512,512]
    const float* query  = (const float*)d_in[1];  // [8,128,512]
    const float* W_h    = (const float*)d_in[2];  // [512,256]
    const float* U_a    = (const float*)d_in[3];  // [512,256]
    const float* V_a    = (const float*)d_in[4];  // [1,256]

    float* ws      = (float*)d_ws;
    float* Ew      = ws;                           // 4096*256 f32
    float* Eu      = ws + 1048576;                 // 1024*256 f32
    float* scoresP = ws + 1310720;                 // 4 * 524288 f32
    short* S       = (short*)(ws + 3407872);
    short* AHi     = S;                            // 5120*512 bf16
    short* ALo     = S + 2621440;
    short* BHi     = S + 5242880;                  // 2*256*512 bf16
    short* BLo     = S + 5505024;

    float* out_c = (float*)d_out;                  // [8,128,512]
    float* out_e = out_c + 8 * 128 * 512;          // [8,128,512]

    hipLaunchKernelGGL(prep, dim3(384), dim3(256), 0, stream,
                       W_h, U_a, values, query, BHi, BLo, AHi, ALo);
    hipLaunchKernelGGL(gemm_mfma, dim3(640), dim3(128), 0, stream,
                       AHi, ALo, BHi, BLo, Ew, Eu);
    hipLaunchKernelGGL(scores_k, dim3(1024), dim3(256), 0, stream,
                       Ew, Eu, V_a, scoresP);
    hipLaunchKernelGGL(softctx, dim3(512), dim3(256), 0, stream,
                       scoresP, values, out_c, out_e);
}